// Round 1
// baseline (1326.941 us; speedup 1.0000x reference)
//
#include <hip/hip_runtime.h>

#define HH 2048
#define WW 4096
#define THR 10.0f

// min over 21x21 window (clipped at borders) of dy^2+dx^2 where img > 0.5,
// else returns 1e12f. Scans outward in |dy|,|dx| with monotone pruning.
__device__ __forceinline__ float window_min_d2(const float* __restrict__ img,
                                               int y, int x) {
    float mind2 = 1e12f;
    for (int ady = 0; ady <= 10; ++ady) {
        float ady2 = (float)(ady * ady);
        if (ady2 >= mind2) break;  // rows farther than current best: done
        for (int s = 0; s < 2; ++s) {
            if (s && ady == 0) break;         // dy=0 only once
            int yy = s ? (y - ady) : (y + ady);
            if (yy < 0 || yy >= HH) continue;
            const float* row = img + (size_t)yy * WW;
            for (int adx = 0; adx <= 10; ++adx) {
                float d2 = ady2 + (float)(adx * adx);
                if (d2 >= mind2) break;       // dx only grows in this row
                int xl = x - adx, xr = x + adx;
                bool hit = (xl >= 0 && row[xl] > 0.5f);
                if (!hit && adx > 0 && xr < WW) hit = (row[xr] > 0.5f);
                if (hit) { mind2 = d2; break; }
            }
        }
    }
    return mind2;
}

__device__ __forceinline__ float waveReduce(float v) {
    #pragma unroll
    for (int o = 32; o > 0; o >>= 1) v += __shfl_down(v, o);
    return v;
}

__global__ __launch_bounds__(256) void dbe_main(const float* __restrict__ gt,
                                                const float* __restrict__ pred,
                                                double* __restrict__ acc) {
    int idx = blockIdx.x * 256 + threadIdx.x;   // grid covers exactly H*W
    int x = idx & (WW - 1);
    int y = idx >> 12;                          // WW = 4096 = 2^12
    float g = gt[idx];
    float p = pred[idx];

    float num = 0.0f;
    float den = g + p;
    float filt = 0.0f;

    if (p > 0.5f) {
        float d2 = window_min_d2(gt, y, x);
        float D = fminf(sqrtf(d2), THR);        // D_gt at this pixel
        num += fminf(D * p, THR);               // ch1
        filt = p * ((D < THR) ? 1.0f : 0.0f);   // pred * mask_D_gt
    }
    if (g > 0.5f) {
        float d2 = window_min_d2(pred, y, x);
        float D = fminf(sqrtf(d2), THR);        // D_est at this pixel
        num += fminf(D * g, THR);               // ch2
    }

    // block reduction: wave shuffle -> LDS -> one double atomicAdd per block
    num = waveReduce(num);
    den = waveReduce(den);
    filt = waveReduce(filt);

    __shared__ float sN[4], sD[4], sF[4];
    int lane = threadIdx.x & 63;
    int wid = threadIdx.x >> 6;
    if (lane == 0) { sN[wid] = num; sD[wid] = den; sF[wid] = filt; }
    __syncthreads();
    if (threadIdx.x == 0) {
        float bn = sN[0] + sN[1] + sN[2] + sN[3];
        float bd = sD[0] + sD[1] + sD[2] + sD[3];
        float bf = sF[0] + sF[1] + sF[2] + sF[3];
        atomicAdd(&acc[0], (double)bn);
        atomicAdd(&acc[1], (double)bd);
        atomicAdd(&acc[2], (double)bf);
    }
}

__global__ void dbe_finalize(const double* __restrict__ acc,
                             float* __restrict__ out) {
    double num = acc[0], den = acc[1], filt = acc[2];
    out[0] = (filt == 0.0) ? THR : (float)(num / den);
}

extern "C" void kernel_launch(void* const* d_in, const int* in_sizes, int n_in,
                              void* d_out, int out_size, void* d_ws, size_t ws_size,
                              hipStream_t stream) {
    const float* gt   = (const float*)d_in[0];
    const float* pred = (const float*)d_in[1];
    float* out = (float*)d_out;
    double* acc = (double*)d_ws;

    hipMemsetAsync(d_ws, 0, 3 * sizeof(double), stream);

    int total = HH * WW;
    int blocks = total / 256;  // 32768, exact
    dbe_main<<<blocks, 256, 0, stream>>>(gt, pred, acc);
    dbe_finalize<<<1, 1, 0, stream>>>(acc, out);
}

// Round 2
// 1286.656 us; speedup vs baseline: 1.0313x; 1.0313x over previous
//
#include <hip/hip_runtime.h>

typedef unsigned long long u64;

#define HH 2048
#define WW 4096
#define MW 66            // u64 words per padded row: 1 guard + 64 data + 1 guard
#define MROWS (HH + 20)  // 10 zero guard rows above and below
#define MASK_WORDS ((size_t)MROWS * MW)
#define THR 10.0f

// ---------------- pack: float image -> 1 bit/pixel mask (ballot) -------------
__global__ __launch_bounds__(256) void pack_masks(const float* __restrict__ gt,
                                                  const float* __restrict__ pred,
                                                  u64* __restrict__ gmask,
                                                  u64* __restrict__ pmask) {
    int idx = blockIdx.x * 256 + threadIdx.x;
    int x = idx & (WW - 1);
    int y = idx >> 12;
    u64 gm = __ballot(gt[idx] > 0.5f);
    u64 pm = __ballot(pred[idx] > 0.5f);
    if ((threadIdx.x & 63) == 0) {
        size_t w = (size_t)(y + 10) * MW + 1 + (x >> 6);
        gmask[w] = gm;
        pmask[w] = pm;
    }
}

// min over 21x21 window of dy^2+dx^2 where mask bit set; large value if empty.
// mask points at word 0 (left guard) of row storage; pixel x lives at bit 64+x
// of its padded row, so the window start (x-10) is at bit b = x + 54 >= 0.
__device__ __forceinline__ int window_min_d2(const u64* __restrict__ mask,
                                             int y, int x) {
    int b = x + 54;
    int w0 = b >> 6;
    int sh = b & 63;
    int mind2 = 1 << 20;
    const u64* rowc = mask + (size_t)(y + 10) * MW;
    #pragma unroll 1
    for (int ady = 0; ady <= 10; ++ady) {
        if (ady * ady >= mind2) break;            // farther rows can't win
        const u64* r0 = rowc - (size_t)ady * MW;  // row y-ady (guard-padded)
        const u64* r1 = rowc + (size_t)ady * MW;  // row y+ady
        u64 a0 = r0[w0] | r1[w0];                 // same |dy| -> OR rows first
        u64 a1 = r0[w0 + 1] | r1[w0 + 1];
        u64 win64 = a0 >> sh;
        if (sh) win64 |= a1 << (64 - sh);
        unsigned w = (unsigned)win64 & 0x1FFFFFu; // bit k <-> dx = k-10
        if (w) {
            unsigned hi = w >> 10;                // dx = 0..10
            unsigned lo = w & 0x3FFu;             // bit j -> dx = j-10
            int mdx = 32;
            if (hi) mdx = __ffs(hi) - 1;          // min dx >= 0
            if (lo) { int m2 = __clz(lo) - 21; if (m2 < mdx) mdx = m2; } // min -dx
            int d2 = ady * ady + mdx * mdx;
            if (d2 < mind2) mind2 = d2;
        }
    }
    return mind2;
}

__device__ __forceinline__ float waveReduce(float v) {
    #pragma unroll
    for (int o = 32; o > 0; o >>= 1) v += __shfl_down(v, o);
    return v;
}

__global__ __launch_bounds__(256) void dbe_main(const u64* __restrict__ gmask,
                                                const u64* __restrict__ pmask,
                                                double* __restrict__ acc) {
    int idx = blockIdx.x * 256 + threadIdx.x;
    int x = idx & (WW - 1);
    int y = idx >> 12;
    size_t wi = (size_t)(y + 10) * MW + 1 + (x >> 6);
    int bit = x & 63;
    bool g = (gmask[wi] >> bit) & 1ull;   // wave-uniform word -> broadcast load
    bool p = (pmask[wi] >> bit) & 1ull;

    float num = 0.0f;
    float den = (g ? 1.0f : 0.0f) + (p ? 1.0f : 0.0f);
    float filt = 0.0f;

    if (p) {                               // ch1: D_gt at pred-fg pixels
        int d2 = window_min_d2(gmask, y, x);
        num += fminf(sqrtf((float)d2), THR);
        if (d2 < 100) filt += 1.0f;        // D_gt < 10 strictly
    }
    if (g) {                               // ch2: D_est at gt-fg pixels
        int d2 = window_min_d2(pmask, y, x);
        num += fminf(sqrtf((float)d2), THR);
    }

    num = waveReduce(num);
    den = waveReduce(den);
    filt = waveReduce(filt);

    __shared__ float sN[4], sD[4], sF[4];
    int lane = threadIdx.x & 63;
    int wid = threadIdx.x >> 6;
    if (lane == 0) { sN[wid] = num; sD[wid] = den; sF[wid] = filt; }
    __syncthreads();
    if (threadIdx.x == 0) {
        atomicAdd(&acc[0], (double)(sN[0] + sN[1] + sN[2] + sN[3]));
        atomicAdd(&acc[1], (double)(sD[0] + sD[1] + sD[2] + sD[3]));
        atomicAdd(&acc[2], (double)(sF[0] + sF[1] + sF[2] + sF[3]));
    }
}

__global__ void dbe_finalize(const double* __restrict__ acc,
                             float* __restrict__ out) {
    out[0] = (acc[2] == 0.0) ? THR : (float)(acc[0] / acc[1]);
}

extern "C" void kernel_launch(void* const* d_in, const int* in_sizes, int n_in,
                              void* d_out, int out_size, void* d_ws, size_t ws_size,
                              hipStream_t stream) {
    const float* gt   = (const float*)d_in[0];
    const float* pred = (const float*)d_in[1];
    float* out = (float*)d_out;

    // workspace layout: [0,24) acc doubles; [64, ...) gmask; then pmask
    double* acc = (double*)d_ws;
    u64* gmask = (u64*)((char*)d_ws + 64);
    u64* pmask = gmask + MASK_WORDS;
    size_t total_bytes = 64 + 2 * MASK_WORDS * sizeof(u64);

    hipMemsetAsync(d_ws, 0, total_bytes, stream);

    int blocks = (HH * WW) / 256;  // 32768, exact
    pack_masks<<<blocks, 256, 0, stream>>>(gt, pred, gmask, pmask);
    dbe_main<<<blocks, 256, 0, stream>>>(gmask, pmask, acc);
    dbe_finalize<<<1, 1, 0, stream>>>(acc, out);
}

// Round 3
// 221.300 us; speedup vs baseline: 5.9961x; 5.8141x over previous
//
#include <hip/hip_runtime.h>

typedef unsigned long long u64;

#define HH 2048
#define WW 4096
#define MW 66            // u64 words per padded row: 1 guard + 64 data + 1 guard
#define MROWS (HH + 20)  // 10 zero guard rows above and below
#define MASK_WORDS ((size_t)MROWS * MW)
#define THR 10.0f
#define NB 4096          // dbe_main blocks
#define BT 256
#define TOTAL (HH * WW)
#define STRIDE (NB * BT)
#define NITER (TOTAL / STRIDE)  // 8

// ---------------- pack: float image -> 1 bit/pixel mask (ballot) -------------
__global__ __launch_bounds__(256) void pack_masks(const float* __restrict__ gt,
                                                  const float* __restrict__ pred,
                                                  u64* __restrict__ gmask,
                                                  u64* __restrict__ pmask) {
    int idx = blockIdx.x * 256 + threadIdx.x;
    int x = idx & (WW - 1);
    int y = idx >> 12;
    u64 gm = __ballot(gt[idx] > 0.5f);
    u64 pm = __ballot(pred[idx] > 0.5f);
    if ((threadIdx.x & 63) == 0) {
        size_t w = (size_t)(y + 10) * MW + 1 + (x >> 6);
        gmask[w] = gm;
        pmask[w] = pm;
    }
}

// min over 21x21 window of dy^2+dx^2 where mask bit set; large value if empty.
__device__ __forceinline__ int window_min_d2(const u64* __restrict__ mask,
                                             int y, int x) {
    int b = x + 54;      // window-start bit in padded row (pixel x at bit 64+x)
    int w0 = b >> 6;
    int sh = b & 63;
    int mind2 = 1 << 20;
    const u64* rowc = mask + (size_t)(y + 10) * MW;
    #pragma unroll 1
    for (int ady = 0; ady <= 10; ++ady) {
        if (ady * ady >= mind2) break;            // farther rows can't win
        const u64* r0 = rowc - (size_t)ady * MW;  // row y-ady (guard-padded)
        const u64* r1 = rowc + (size_t)ady * MW;  // row y+ady
        u64 a0 = r0[w0] | r1[w0];                 // same |dy| -> OR rows first
        u64 a1 = r0[w0 + 1] | r1[w0 + 1];
        u64 win64 = a0 >> sh;
        if (sh) win64 |= a1 << (64 - sh);
        unsigned w = (unsigned)win64 & 0x1FFFFFu; // bit k <-> dx = k-10
        if (w) {
            unsigned hi = w >> 10;                // dx = 0..10
            unsigned lo = w & 0x3FFu;             // bit j -> dx = j-10
            int mdx = 32;
            if (hi) mdx = __ffs(hi) - 1;          // min dx >= 0
            if (lo) { int m2 = __clz(lo) - 21; if (m2 < mdx) mdx = m2; } // min -dx
            int d2 = ady * ady + mdx * mdx;
            if (d2 < mind2) mind2 = d2;
        }
    }
    return mind2;
}

__device__ __forceinline__ float waveReduceF(float v) {
    #pragma unroll
    for (int o = 32; o > 0; o >>= 1) v += __shfl_down(v, o);
    return v;
}

__global__ __launch_bounds__(BT) void dbe_main(const u64* __restrict__ gmask,
                                               const u64* __restrict__ pmask,
                                               float* __restrict__ pn,
                                               float* __restrict__ pd,
                                               float* __restrict__ pf) {
    int tid = blockIdx.x * BT + threadIdx.x;
    float num = 0.0f, den = 0.0f, filt = 0.0f;

    #pragma unroll 1
    for (int i = 0; i < NITER; ++i) {
        int idx = tid + i * STRIDE;
        int x = idx & (WW - 1);
        int y = idx >> 12;
        size_t wi = (size_t)(y + 10) * MW + 1 + (x >> 6);
        int bit = x & 63;
        bool g = (gmask[wi] >> bit) & 1ull;  // wave-uniform word -> broadcast
        bool p = (pmask[wi] >> bit) & 1ull;
        den += (g ? 1.0f : 0.0f) + (p ? 1.0f : 0.0f);
        if (p) {                              // ch1: D_gt at pred-fg pixels
            int d2 = window_min_d2(gmask, y, x);
            num += fminf(sqrtf((float)d2), THR);
            if (d2 < 100) filt += 1.0f;       // D_gt < 10 strictly
        }
        if (g) {                              // ch2: D_est at gt-fg pixels
            int d2 = window_min_d2(pmask, y, x);
            num += fminf(sqrtf((float)d2), THR);
        }
    }

    num = waveReduceF(num);
    den = waveReduceF(den);
    filt = waveReduceF(filt);

    __shared__ float sN[4], sD[4], sF[4];
    int lane = threadIdx.x & 63;
    int wid = threadIdx.x >> 6;
    if (lane == 0) { sN[wid] = num; sD[wid] = den; sF[wid] = filt; }
    __syncthreads();
    if (threadIdx.x == 0) {                   // plain stores, no atomics
        pn[blockIdx.x] = sN[0] + sN[1] + sN[2] + sN[3];
        pd[blockIdx.x] = sD[0] + sD[1] + sD[2] + sD[3];
        pf[blockIdx.x] = sF[0] + sF[1] + sF[2] + sF[3];
    }
}

__global__ __launch_bounds__(BT) void dbe_reduce(const float* __restrict__ pn,
                                                 const float* __restrict__ pd,
                                                 const float* __restrict__ pf,
                                                 float* __restrict__ out) {
    double n = 0.0, d = 0.0, f = 0.0;
    for (int i = threadIdx.x; i < NB; i += BT) {
        n += (double)pn[i]; d += (double)pd[i]; f += (double)pf[i];
    }
    #pragma unroll
    for (int o = 32; o > 0; o >>= 1) {
        n += __shfl_down(n, o); d += __shfl_down(d, o); f += __shfl_down(f, o);
    }
    __shared__ double sn[4], sd[4], sf[4];
    int lane = threadIdx.x & 63;
    int wid = threadIdx.x >> 6;
    if (lane == 0) { sn[wid] = n; sd[wid] = d; sf[wid] = f; }
    __syncthreads();
    if (threadIdx.x == 0) {
        double N = sn[0] + sn[1] + sn[2] + sn[3];
        double D = sd[0] + sd[1] + sd[2] + sd[3];
        double F = sf[0] + sf[1] + sf[2] + sf[3];
        out[0] = (F == 0.0) ? THR : (float)(N / D);
    }
}

extern "C" void kernel_launch(void* const* d_in, const int* in_sizes, int n_in,
                              void* d_out, int out_size, void* d_ws, size_t ws_size,
                              hipStream_t stream) {
    const float* gt   = (const float*)d_in[0];
    const float* pred = (const float*)d_in[1];
    float* out = (float*)d_out;

    // workspace: pn[NB] pd[NB] pf[NB] (48 KB, 64-aligned) | gmask | pmask
    float* pn = (float*)d_ws;
    float* pd = pn + NB;
    float* pf = pd + NB;
    u64* gmask = (u64*)((char*)d_ws + 3 * NB * sizeof(float));
    u64* pmask = gmask + MASK_WORDS;

    // zero only the mask region (guard rows/words must be 0; partials are
    // written unconditionally by every block)
    hipMemsetAsync(gmask, 0, 2 * MASK_WORDS * sizeof(u64), stream);

    pack_masks<<<TOTAL / 256, 256, 0, stream>>>(gt, pred, gmask, pmask);
    dbe_main<<<NB, BT, 0, stream>>>(gmask, pmask, pn, pd, pf);
    dbe_reduce<<<1, BT, 0, stream>>>(pn, pd, pf, out);
}